// Round 3
// baseline (265.135 us; speedup 1.0000x reference)
//
#include <hip/hip_runtime.h>
#include <stdint.h>

// GCN 2-hop: GEMMs via bf16 MFMA, aggregation via on-device CSR (no atomics in
// the hot loop), fused bias/relu/residual/LayerNorm epilogues.
// R3: 6 dispatches (+1 memset): edge-accum folded into prep (deg/cnt via
// memset, dinv=rsqrt(1+sum)); single-pass 20-items/thread scan; CSR-fill
// merged into the layer-1 GEMM dispatch; bf16 RES/h1 intermediates; agg
// gather unrolled x8.

constexpr int DIN = 128;
constexpr int DH  = 256;
#define LN_EPS 1e-5f

typedef __attribute__((ext_vector_type(8))) short bf16x8;  // 8 bf16 = 4 VGPR
typedef __attribute__((ext_vector_type(4))) short bf16x4;  // 8 bytes
typedef __attribute__((ext_vector_type(4))) float f32x4;

__device__ __forceinline__ short f2bf(float f) {
  union { float f; unsigned u; } v; v.f = f;
  unsigned r = v.u + 0x7fffu + ((v.u >> 16) & 1u);  // RNE
  return (short)(r >> 16);
}
__device__ __forceinline__ float bf2f(short b) {
  union { unsigned u; float f; } v; v.u = ((unsigned)(unsigned short)b) << 16;
  return v.f;
}

// edge_index may be int32 (JAX x64 off) or int64. Wave-level probe: sample 64
// spread-out odd 32-bit words of the src half; all-zero <=> int64 high words.
// Call while the whole (possibly partial) wave is active; ballot over the
// active lanes is sufficient.
__device__ __forceinline__ int probe_m64(const unsigned* ei, int E) {
  int lane = threadIdx.x & 63;
  long long stride = (E >= 64) ? (E / 64) : 1;
  long long li = (long long)lane * stride;
  if (li >= E) li = 0;
  unsigned v = ei[2 * li + 1];
  return __ballot(v != 0u) == 0ull;
}

__device__ __forceinline__ int eidx(const void* ei, long long e, int m64) {
  return m64 ? (int)((const long long*)ei)[e] : ((const int*)ei)[e];
}

// ------- prep: x->bf16 + 3 weight transposes + edge accumulation -------
// deg/cnt are memset-0 before this kernel; self-loop +1 is added in k_scan.

__global__ __launch_bounds__(256) void k_prep(const float* __restrict__ x,
                                              short* __restrict__ xb,
                                              const float* __restrict__ W1,
                                              const float* __restrict__ Wres,
                                              const float* __restrict__ W2,
                                              short* __restrict__ W1t,
                                              short* __restrict__ Wrt,
                                              short* __restrict__ W2t,
                                              const void* ei,
                                              const float* __restrict__ ew,
                                              float* deg, int* cnt,
                                              int N, int E) {
  const int NXV = N * DIN / 8;           // x in 8-float chunks
  const int NW  = DIN * DH;              // 32768
  const int NW2 = DH * DH;               // 65536
  int idx = blockIdx.x * 256 + threadIdx.x;
  if (idx < NXV) {
    f32x4 a = ((const f32x4*)x)[idx * 2];
    f32x4 b = ((const f32x4*)x)[idx * 2 + 1];
    bf16x8 o;
    o[0] = f2bf(a[0]); o[1] = f2bf(a[1]); o[2] = f2bf(a[2]); o[3] = f2bf(a[3]);
    o[4] = f2bf(b[0]); o[5] = f2bf(b[1]); o[6] = f2bf(b[2]); o[7] = f2bf(b[3]);
    ((bf16x8*)xb)[idx] = o;
    return;
  }
  idx -= NXV;
  if (idx < NW) {  // W1t[n][k] = W1[k][n], write-coalesced
    int n = idx / DIN, k = idx % DIN;
    W1t[idx] = f2bf(W1[k * DH + n]);
    return;
  }
  idx -= NW;
  if (idx < NW) {
    int n = idx / DIN, k = idx % DIN;
    Wrt[idx] = f2bf(Wres[k * DH + n]);
    return;
  }
  idx -= NW;
  if (idx < NW2) {
    int n = idx / DH, k = idx % DH;
    W2t[idx] = f2bf(W2[k * DH + n]);
    return;
  }
  idx -= NW2;
  // edge accumulation section
  int m64 = probe_m64((const unsigned*)ei, E);
  if (idx < E) {
    int d = eidx(ei, (long long)E + idx, m64);
    atomicAdd(&deg[d], ew[idx]);
    atomicAdd(&cnt[d], 1);
  }
}

// ---- single block, single pass: dinv=rsqrt(1+deg); scan cnt->rowptr/cursor --
// 1024 threads x ITEMS contiguous elements each; per-thread serial prefix,
// wave shfl-scan of totals, LDS scan of 16 wave totals.

__global__ __launch_bounds__(1024) void k_scan(const int* __restrict__ cnt,
                                               float* deg, int* rowptr,
                                               int* cursor, int n) {
  for (int i = threadIdx.x; i < n; i += 1024) deg[i] = rsqrtf(1.0f + deg[i]);

  constexpr int MAXI = 32;
  int items = (n + 1023) / 1024;         // 20 for N=20000
  int tid = threadIdx.x, lane = tid & 63, wv = tid >> 6;
  int base = tid * items;
  int v[MAXI];
  int tot = 0;
#pragma unroll 4
  for (int j = 0; j < items; ++j) {
    int i = base + j;
    v[j] = (i < n) ? cnt[i] : 0;
    tot += v[j];
  }
  // wave inclusive scan of tot
  int sc = tot;
#pragma unroll
  for (int off = 1; off < 64; off <<= 1) {
    int t = __shfl_up(sc, off, 64);
    if (lane >= off) sc += t;
  }
  __shared__ int wsum[16];
  if (lane == 63) wsum[wv] = sc;
  __syncthreads();
  if (wv == 0 && lane < 16) {
    int s = wsum[lane];
#pragma unroll
    for (int off = 1; off < 16; off <<= 1) {
      int t = __shfl_up(s, off, 64);
      if (lane >= off) s += t;
    }
    wsum[lane] = s;
  }
  __syncthreads();
  int prefix = (sc - tot) + ((wv > 0) ? wsum[wv - 1] : 0);  // exclusive
  if (tid == 0) { rowptr[0] = 0; cursor[0] = 0; }
  int run = prefix;
#pragma unroll 4
  for (int j = 0; j < items; ++j) {
    int i = base + j;
    run += v[j];
    if (i < n) { rowptr[i + 1] = run; cursor[i + 1] = run; }
  }
}

// ------- merged dispatch: layer-1 GEMM blocks + CSR-fill blocks -------
// blocks [0, GB): H1 = A@W1t^T (bf16), RESb = A@Wrt^T + bres (bf16)
// blocks [GB, GB+FB): CSR fill (independent work, hides under the GEMM)

__global__ __launch_bounds__(256) void k_gemm_l1_fill(
    const short* __restrict__ A, const short* __restrict__ B1,
    const short* __restrict__ Br, const float* __restrict__ bres,
    short* __restrict__ H1, short* __restrict__ RESb, int M, int MB,
    const void* ei, const float* __restrict__ ew,
    const float* __restrict__ dinv, int* cursor, int* srcs, float* norms,
    int E) {
  constexpr int K = DIN;
  int GB = MB * 4;
  if ((int)blockIdx.x >= GB) {
    // ---- fill path ----
    int m64 = probe_m64((const unsigned*)ei, E);
    int e = ((int)blockIdx.x - GB) * 256 + threadIdx.x;
    if (e >= E) return;
    int s = eidx(ei, e, m64);
    int d = eidx(ei, (long long)E + e, m64);
    int p = atomicAdd(&cursor[d], 1);
    srcs[p] = s;
    norms[p] = dinv[s] * ew[e] * dinv[d];
    return;
  }
  int mb = (int)blockIdx.x % MB, nbk = (int)blockIdx.x / MB;
  int tid = threadIdx.x;
  int wave = tid >> 6, lane = tid & 63;
  int lr = lane & 15, lg = lane >> 4;
  int bm = mb * 64 + (wave >> 1) * 32;
  int bn = nbk * 64 + (wave & 1) * 32;

  int r0 = min(bm + lr, M - 1);
  int r1 = min(bm + 16 + lr, M - 1);
  const short* a0p = A + (long long)r0 * K + lg * 8;
  const short* a1p = A + (long long)r1 * K + lg * 8;
  const short* b10p = B1 + (long long)(bn + lr) * K + lg * 8;
  const short* b11p = B1 + (long long)(bn + 16 + lr) * K + lg * 8;
  const short* br0p = Br + (long long)(bn + lr) * K + lg * 8;
  const short* br1p = Br + (long long)(bn + 16 + lr) * K + lg * 8;

  f32x4 a1c[2][2] = {}, arc[2][2] = {};
#pragma unroll
  for (int ks = 0; ks < K / 32; ++ks) {
    bf16x8 a0 = *(const bf16x8*)(a0p + ks * 32);
    bf16x8 a1 = *(const bf16x8*)(a1p + ks * 32);
    bf16x8 p0 = *(const bf16x8*)(b10p + ks * 32);
    bf16x8 p1 = *(const bf16x8*)(b11p + ks * 32);
    bf16x8 q0 = *(const bf16x8*)(br0p + ks * 32);
    bf16x8 q1 = *(const bf16x8*)(br1p + ks * 32);
    a1c[0][0] = __builtin_amdgcn_mfma_f32_16x16x32_bf16(a0, p0, a1c[0][0], 0, 0, 0);
    a1c[0][1] = __builtin_amdgcn_mfma_f32_16x16x32_bf16(a0, p1, a1c[0][1], 0, 0, 0);
    a1c[1][0] = __builtin_amdgcn_mfma_f32_16x16x32_bf16(a1, p0, a1c[1][0], 0, 0, 0);
    a1c[1][1] = __builtin_amdgcn_mfma_f32_16x16x32_bf16(a1, p1, a1c[1][1], 0, 0, 0);
    arc[0][0] = __builtin_amdgcn_mfma_f32_16x16x32_bf16(a0, q0, arc[0][0], 0, 0, 0);
    arc[0][1] = __builtin_amdgcn_mfma_f32_16x16x32_bf16(a0, q1, arc[0][1], 0, 0, 0);
    arc[1][0] = __builtin_amdgcn_mfma_f32_16x16x32_bf16(a1, q0, arc[1][0], 0, 0, 0);
    arc[1][1] = __builtin_amdgcn_mfma_f32_16x16x32_bf16(a1, q1, arc[1][1], 0, 0, 0);
  }

#pragma unroll
  for (int mi = 0; mi < 2; ++mi)
#pragma unroll
    for (int ni = 0; ni < 2; ++ni)
#pragma unroll
      for (int j = 0; j < 4; ++j) {
        int row = bm + mi * 16 + lg * 4 + j;
        int col = bn + ni * 16 + lr;
        if (row < M) {
          H1[(long long)row * DH + col] = f2bf(a1c[mi][ni][j]);
          RESb[(long long)row * DH + col] = f2bf(arc[mi][ni][j] + bres[col]);
        }
      }
}

// ---------------- layer-2 GEMM: H2 = A@W2t^T (bf16 out) ----------------

__global__ __launch_bounds__(256) void k_gemm2(const short* __restrict__ A,
                                               const short* __restrict__ Bt,
                                               short* __restrict__ outb, int M) {
  constexpr int K = DH;
  int tid = threadIdx.x;
  int wave = tid >> 6, lane = tid & 63;
  int lr = lane & 15, lg = lane >> 4;
  int bm = blockIdx.x * 64 + (wave >> 1) * 32;
  int bn = blockIdx.y * 64 + (wave & 1) * 32;

  int r0 = min(bm + lr, M - 1);
  int r1 = min(bm + 16 + lr, M - 1);
  const short* a0p = A + (long long)r0 * K + lg * 8;
  const short* a1p = A + (long long)r1 * K + lg * 8;
  const short* b0p = Bt + (long long)(bn + lr) * K + lg * 8;
  const short* b1p = Bt + (long long)(bn + 16 + lr) * K + lg * 8;

  f32x4 acc[2][2] = {};
#pragma unroll
  for (int ks = 0; ks < K / 32; ++ks) {
    bf16x8 a0 = *(const bf16x8*)(a0p + ks * 32);
    bf16x8 a1 = *(const bf16x8*)(a1p + ks * 32);
    bf16x8 b0 = *(const bf16x8*)(b0p + ks * 32);
    bf16x8 b1 = *(const bf16x8*)(b1p + ks * 32);
    acc[0][0] = __builtin_amdgcn_mfma_f32_16x16x32_bf16(a0, b0, acc[0][0], 0, 0, 0);
    acc[0][1] = __builtin_amdgcn_mfma_f32_16x16x32_bf16(a0, b1, acc[0][1], 0, 0, 0);
    acc[1][0] = __builtin_amdgcn_mfma_f32_16x16x32_bf16(a1, b0, acc[1][0], 0, 0, 0);
    acc[1][1] = __builtin_amdgcn_mfma_f32_16x16x32_bf16(a1, b1, acc[1][1], 0, 0, 0);
  }

#pragma unroll
  for (int mi = 0; mi < 2; ++mi)
#pragma unroll
    for (int ni = 0; ni < 2; ++ni)
#pragma unroll
      for (int j = 0; j < 4; ++j) {
        int row = bm + mi * 16 + lg * 4 + j;
        int col = bn + ni * 16 + lr;
        if (row < M) outb[(long long)row * DH + col] = f2bf(acc[mi][ni][j]);
      }
}

// ------------- fused aggregation + bias (+relu) + residual + LayerNorm ------
// 4 waves/WG, one wave per destination node; lane owns 4 of 256 dims.
// Gather unrolled x8 for memory-level parallelism. Residual may be bf16.

template <bool RELU, bool RESBF>
__global__ __launch_bounds__(256) void k_agg_ln(
    const short* __restrict__ H, const void* __restrict__ resid,
    const float* __restrict__ bias, const float* __restrict__ gamma,
    const float* __restrict__ beta, const int* __restrict__ rowptr,
    const int* __restrict__ srcs, const float* __restrict__ norms,
    const float* __restrict__ dinv, float* __restrict__ out_f,
    short* __restrict__ out_bf, int n) {
  int wv = threadIdx.x >> 6, lane = threadIdx.x & 63;
  int i = blockIdx.x * 4 + wv;
  if (i >= n) return;
  int d = lane * 4;

  float di = dinv[i];
  float acc0, acc1, acc2, acc3;
  {
    bf16x4 hv = *(const bf16x4*)(H + (long long)i * DH + d);
    float sw = di * di;  // self-loop norm
    acc0 = sw * bf2f(hv[0]); acc1 = sw * bf2f(hv[1]);
    acc2 = sw * bf2f(hv[2]); acc3 = sw * bf2f(hv[3]);
  }
  int e = rowptr[i], end = rowptr[i + 1];
  for (; e + 8 <= end; e += 8) {
    int s0 = srcs[e],     s1 = srcs[e + 1], s2 = srcs[e + 2], s3 = srcs[e + 3];
    int s4 = srcs[e + 4], s5 = srcs[e + 5], s6 = srcs[e + 6], s7 = srcs[e + 7];
    bf16x4 v0 = *(const bf16x4*)(H + (long long)s0 * DH + d);
    bf16x4 v1 = *(const bf16x4*)(H + (long long)s1 * DH + d);
    bf16x4 v2 = *(const bf16x4*)(H + (long long)s2 * DH + d);
    bf16x4 v3 = *(const bf16x4*)(H + (long long)s3 * DH + d);
    bf16x4 v4 = *(const bf16x4*)(H + (long long)s4 * DH + d);
    bf16x4 v5 = *(const bf16x4*)(H + (long long)s5 * DH + d);
    bf16x4 v6 = *(const bf16x4*)(H + (long long)s6 * DH + d);
    bf16x4 v7 = *(const bf16x4*)(H + (long long)s7 * DH + d);
    float n0 = norms[e],     n1 = norms[e + 1], n2 = norms[e + 2], n3 = norms[e + 3];
    float n4 = norms[e + 4], n5 = norms[e + 5], n6 = norms[e + 6], n7 = norms[e + 7];
    acc0 += n0 * bf2f(v0[0]); acc1 += n0 * bf2f(v0[1]);
    acc2 += n0 * bf2f(v0[2]); acc3 += n0 * bf2f(v0[3]);
    acc0 += n1 * bf2f(v1[0]); acc1 += n1 * bf2f(v1[1]);
    acc2 += n1 * bf2f(v1[2]); acc3 += n1 * bf2f(v1[3]);
    acc0 += n2 * bf2f(v2[0]); acc1 += n2 * bf2f(v2[1]);
    acc2 += n2 * bf2f(v2[2]); acc3 += n2 * bf2f(v2[3]);
    acc0 += n3 * bf2f(v3[0]); acc1 += n3 * bf2f(v3[1]);
    acc2 += n3 * bf2f(v3[2]); acc3 += n3 * bf2f(v3[3]);
    acc0 += n4 * bf2f(v4[0]); acc1 += n4 * bf2f(v4[1]);
    acc2 += n4 * bf2f(v4[2]); acc3 += n4 * bf2f(v4[3]);
    acc0 += n5 * bf2f(v5[0]); acc1 += n5 * bf2f(v5[1]);
    acc2 += n5 * bf2f(v5[2]); acc3 += n5 * bf2f(v5[3]);
    acc0 += n6 * bf2f(v6[0]); acc1 += n6 * bf2f(v6[1]);
    acc2 += n6 * bf2f(v6[2]); acc3 += n6 * bf2f(v6[3]);
    acc0 += n7 * bf2f(v7[0]); acc1 += n7 * bf2f(v7[1]);
    acc2 += n7 * bf2f(v7[2]); acc3 += n7 * bf2f(v7[3]);
  }
  for (; e < end; ++e) {
    int s = srcs[e];
    float nm = norms[e];
    bf16x4 v = *(const bf16x4*)(H + (long long)s * DH + d);
    acc0 += nm * bf2f(v[0]); acc1 += nm * bf2f(v[1]);
    acc2 += nm * bf2f(v[2]); acc3 += nm * bf2f(v[3]);
  }

  float r0, r1, r2, r3;
  if (RESBF) {
    bf16x4 rv = *(const bf16x4*)((const short*)resid + (long long)i * DH + d);
    r0 = bf2f(rv[0]); r1 = bf2f(rv[1]); r2 = bf2f(rv[2]); r3 = bf2f(rv[3]);
  } else {
    f32x4 rv = *(const f32x4*)((const float*)resid + (long long)i * DH + d);
    r0 = rv[0]; r1 = rv[1]; r2 = rv[2]; r3 = rv[3];
  }
  f32x4 bv = *(const f32x4*)(bias + d);
  float t0 = acc0 + bv[0], t1 = acc1 + bv[1], t2 = acc2 + bv[2], t3 = acc3 + bv[3];
  if (RELU) {
    t0 = fmaxf(t0, 0.f); t1 = fmaxf(t1, 0.f);
    t2 = fmaxf(t2, 0.f); t3 = fmaxf(t3, 0.f);
  }
  t0 += r0; t1 += r1; t2 += r2; t3 += r3;

  float s1 = t0 + t1 + t2 + t3;
  float s2 = t0 * t0 + t1 * t1 + t2 * t2 + t3 * t3;
#pragma unroll
  for (int m = 1; m < 64; m <<= 1) {
    s1 += __shfl_xor(s1, m, 64);
    s2 += __shfl_xor(s2, m, 64);
  }
  float mu = s1 * (1.f / 256.f);
  float var = s2 * (1.f / 256.f) - mu * mu;
  float rs = rsqrtf(var + LN_EPS);

  f32x4 gv = *(const f32x4*)(gamma + d);
  f32x4 be = *(const f32x4*)(beta + d);
  f32x4 y;
  y[0] = (t0 - mu) * rs * gv[0] + be[0];
  y[1] = (t1 - mu) * rs * gv[1] + be[1];
  y[2] = (t2 - mu) * rs * gv[2] + be[2];
  y[3] = (t3 - mu) * rs * gv[3] + be[3];
  if (out_f) *(f32x4*)(out_f + (long long)i * DH + d) = y;
  if (out_bf) {
    bf16x4 ob;
    ob[0] = f2bf(y[0]); ob[1] = f2bf(y[1]);
    ob[2] = f2bf(y[2]); ob[3] = f2bf(y[3]);
    *(bf16x4*)(out_bf + (long long)i * DH + d) = ob;
  }
}

// ---------------- launcher ----------------

extern "C" void kernel_launch(void* const* d_in, const int* in_sizes, int n_in,
                              void* d_out, int out_size, void* d_ws,
                              size_t ws_size, hipStream_t stream) {
  const float* x    = (const float*)d_in[0];
  const void*  ei   = d_in[1];
  const float* ew   = (const float*)d_in[2];
  const float* W1   = (const float*)d_in[3];
  const float* b1   = (const float*)d_in[4];
  const float* W2   = (const float*)d_in[5];
  const float* b2   = (const float*)d_in[6];
  const float* Wres = (const float*)d_in[7];
  const float* bres = (const float*)d_in[8];
  const float* g1   = (const float*)d_in[9];
  const float* be1  = (const float*)d_in[10];
  const float* g2   = (const float*)d_in[11];
  const float* be2  = (const float*)d_in[12];

  const int N = in_sizes[0] / DIN;
  const int E = in_sizes[2];

  char* ws = (char*)d_ws;
  auto alloc = [&](size_t bytes) -> char* {
    char* p = ws;
    ws += (bytes + 255) & ~(size_t)255;
    return p;
  };
  short* xb     = (short*)alloc((size_t)N * DIN * 2);
  short* W1t    = (short*)alloc((size_t)DIN * DH * 2);
  short* Wrt    = (short*)alloc((size_t)DIN * DH * 2);
  short* W2t    = (short*)alloc((size_t)DH * DH * 2);
  short* Hb     = (short*)alloc((size_t)N * DH * 2);  // H1bf, reused as H2bf
  short* RESb   = (short*)alloc((size_t)N * DH * 2);
  short* h1b    = (short*)alloc((size_t)N * DH * 2);
  int*   cnt    = (int*)alloc((size_t)N * 8);         // cnt[N] + deg[N] contiguous
  float* deg    = (float*)(cnt + N);                  // becomes dinv in k_scan
  int*   rowptr = (int*)alloc((size_t)(N + 1) * 4);
  int*   cursor = (int*)alloc((size_t)(N + 1) * 4);
  int*   srcs   = (int*)alloc((size_t)E * 4);
  float* norms  = (float*)alloc((size_t)E * 4);

  hipMemsetAsync(cnt, 0, (size_t)N * 8, stream);

  // prep: x cvt + weight transposes + edge accumulation, one kernel
  int prep_items = N * DIN / 8 + 2 * DIN * DH + DH * DH + E;
  k_prep<<<(prep_items + 255) / 256, 256, 0, stream>>>(
      x, xb, W1, Wres, W2, W1t, Wrt, W2t, ei, ew, deg, cnt, N, E);
  k_scan<<<1, 1024, 0, stream>>>(cnt, deg, rowptr, cursor, N);

  const int MB = (N + 63) / 64;          // 313
  const int FB = (E + 255) / 256;        // 1250
  k_gemm_l1_fill<<<MB * 4 + FB, 256, 0, stream>>>(
      xb, W1t, Wrt, bres, Hb, RESb, N, MB, ei, ew, deg, cursor, srcs, norms, E);
  k_agg_ln<true, true><<<(N + 3) / 4, 256, 0, stream>>>(
      Hb, RESb, b1, g1, be1, rowptr, srcs, norms, deg, nullptr, h1b, N);

  dim3 gg(MB, DH / 64);
  k_gemm2<<<gg, 256, 0, stream>>>(h1b, W2t, Hb, N);
  k_agg_ln<false, true><<<(N + 3) / 4, 256, 0, stream>>>(
      Hb, h1b, b2, g2, be2, rowptr, srcs, norms, deg, (float*)d_out, nullptr, N);
}

// Round 4
// 262.500 us; speedup vs baseline: 1.0100x; 1.0100x over previous
//
#include <hip/hip_runtime.h>
#include <stdint.h>

// GCN 2-hop, R4: reordered dataflow S@(x@W) -> (S@x)@W.
//   memset -> prep -> scan -> fill -> agg_x(128d) -> gemm_ln1(dual-A, fused LN)
//          -> agg_h1(256d) -> gemm_ln2(fused residual+LN)
// Aggregation = pure bf16 row gather (CSR by dst, half-wave per edge).
// GEMMs: 1 wave = 16 rows x 256 cols (16 MFMA frags), LN in 16-lane shfl group.

constexpr int DIN = 128;
constexpr int DH  = 256;
#define LN_EPS 1e-5f

typedef __attribute__((ext_vector_type(8))) short bf16x8;  // 16 B
typedef __attribute__((ext_vector_type(4))) short bf16x4;  // 8 B
typedef __attribute__((ext_vector_type(4))) float f32x4;

__device__ __forceinline__ short f2bf(float f) {
  union { float f; unsigned u; } v; v.f = f;
  unsigned r = v.u + 0x7fffu + ((v.u >> 16) & 1u);  // RNE
  return (short)(r >> 16);
}
__device__ __forceinline__ float bf2f(short b) {
  union { unsigned u; float f; } v; v.u = ((unsigned)(unsigned short)b) << 16;
  return v.f;
}

// edge_index may be int32 (JAX x64 off) or int64: sample odd 32-bit words of
// the src half; all-zero <=> int64. Call with the wave converged.
__device__ __forceinline__ int probe_m64(const unsigned* ei, int E) {
  int lane = threadIdx.x & 63;
  long long stride = (E >= 64) ? (E / 64) : 1;
  long long li = (long long)lane * stride;
  if (li >= E) li = 0;
  unsigned v = ei[2 * li + 1];
  return __ballot(v != 0u) == 0ull;
}

__device__ __forceinline__ int eidx(const void* ei, long long e, int m64) {
  return m64 ? (int)((const long long*)ei)[e] : ((const int*)ei)[e];
}

// ------- prep: x->bf16 + 3 weight transposes + edge accumulation -------
// deg/cnt memset-0 before this kernel; self-loop +1 added in k_scan.

__global__ __launch_bounds__(256) void k_prep(const float* __restrict__ x,
                                              short* __restrict__ xb,
                                              const float* __restrict__ W1,
                                              const float* __restrict__ Wres,
                                              const float* __restrict__ W2,
                                              short* __restrict__ W1t,
                                              short* __restrict__ Wrt,
                                              short* __restrict__ W2t,
                                              const void* ei,
                                              const float* __restrict__ ew,
                                              float* deg, int* cnt,
                                              int N, int E) {
  const int NXV = N * DIN / 8;
  const int NW  = DIN * DH;              // 32768
  const int NW2 = DH * DH;               // 65536
  int idx = blockIdx.x * 256 + threadIdx.x;
  if (idx < NXV) {
    f32x4 a = ((const f32x4*)x)[idx * 2];
    f32x4 b = ((const f32x4*)x)[idx * 2 + 1];
    bf16x8 o;
    o[0] = f2bf(a[0]); o[1] = f2bf(a[1]); o[2] = f2bf(a[2]); o[3] = f2bf(a[3]);
    o[4] = f2bf(b[0]); o[5] = f2bf(b[1]); o[6] = f2bf(b[2]); o[7] = f2bf(b[3]);
    ((bf16x8*)xb)[idx] = o;
    return;
  }
  idx -= NXV;
  if (idx < NW) {
    int n = idx / DIN, k = idx % DIN;
    W1t[idx] = f2bf(W1[k * DH + n]);
    return;
  }
  idx -= NW;
  if (idx < NW) {
    int n = idx / DIN, k = idx % DIN;
    Wrt[idx] = f2bf(Wres[k * DH + n]);
    return;
  }
  idx -= NW;
  if (idx < NW2) {
    int n = idx / DH, k = idx % DH;
    W2t[idx] = f2bf(W2[k * DH + n]);
    return;
  }
  idx -= NW2;
  int m64 = probe_m64((const unsigned*)ei, E);
  if (idx < E) {
    int d = eidx(ei, (long long)E + idx, m64);
    atomicAdd(&deg[d], ew[idx]);
    atomicAdd(&cnt[d], 1);
  }
}

// ---- single block, single pass: dinv=rsqrt(1+deg); scan cnt->rowptr/cursor --

__global__ __launch_bounds__(1024) void k_scan(const int* __restrict__ cnt,
                                               float* deg, int* rowptr,
                                               int* cursor, int n) {
  for (int i = threadIdx.x; i < n; i += 1024) deg[i] = rsqrtf(1.0f + deg[i]);

  constexpr int MAXI = 32;
  int items = (n + 1023) / 1024;         // 20 for N=20000
  int tid = threadIdx.x, lane = tid & 63, wv = tid >> 6;
  int base = tid * items;
  int v[MAXI];
  int tot = 0;
#pragma unroll 4
  for (int j = 0; j < items; ++j) {
    int i = base + j;
    v[j] = (i < n) ? cnt[i] : 0;
    tot += v[j];
  }
  int sc = tot;
#pragma unroll
  for (int off = 1; off < 64; off <<= 1) {
    int t = __shfl_up(sc, off, 64);
    if (lane >= off) sc += t;
  }
  __shared__ int wsum[16];
  if (lane == 63) wsum[wv] = sc;
  __syncthreads();
  if (wv == 0 && lane < 16) {
    int s = wsum[lane];
#pragma unroll
    for (int off = 1; off < 16; off <<= 1) {
      int t = __shfl_up(s, off, 64);
      if (lane >= off) s += t;
    }
    wsum[lane] = s;
  }
  __syncthreads();
  int prefix = (sc - tot) + ((wv > 0) ? wsum[wv - 1] : 0);
  if (tid == 0) { rowptr[0] = 0; cursor[0] = 0; }
  int run = prefix;
#pragma unroll 4
  for (int j = 0; j < items; ++j) {
    int i = base + j;
    run += v[j];
    if (i < n) { rowptr[i + 1] = run; cursor[i + 1] = run; }
  }
}

// ---------------- CSR fill ----------------

__global__ __launch_bounds__(256) void k_fill(const void* ei,
                                              const float* __restrict__ w,
                                              const float* __restrict__ dinv,
                                              int* cursor, int* srcs,
                                              float* norms, int E) {
  int m64 = probe_m64((const unsigned*)ei, E);
  int e = blockIdx.x * 256 + threadIdx.x;
  if (e >= E) return;
  int s = eidx(ei, e, m64);
  int d = eidx(ei, (long long)E + e, m64);
  int p = atomicAdd(&cursor[d], 1);
  srcs[p] = s;
  norms[p] = dinv[s] * w[e] * dinv[d];
}

// ------- pure gather-aggregate: out[i] = dinv[i]^2*T[i] + sum norm*T[src] ----
// 4 waves/block, 1 wave per dst node; half-wave per edge (lane covers DPL dims
// via one 8B/16B load); shfl_xor(32) combines halves.

__global__ __launch_bounds__(256) void k_agg128(const short* __restrict__ T,
                                                const int* __restrict__ rowptr,
                                                const int* __restrict__ srcs,
                                                const float* __restrict__ norms,
                                                const float* __restrict__ dinv,
                                                short* __restrict__ out, int n) {
  int wv = threadIdx.x >> 6, lane = threadIdx.x & 63;
  int i = blockIdx.x * 4 + wv;
  if (i >= n) return;
  int h = lane >> 5;
  int c = (lane & 31) * 4;
  float a0 = 0.f, a1 = 0.f, a2 = 0.f, a3 = 0.f;
  int e = rowptr[i] + h, end = rowptr[i + 1];
  for (; e + 6 < end; e += 8) {
    int s0 = srcs[e], s1 = srcs[e + 2], s2 = srcs[e + 4], s3 = srcs[e + 6];
    float w0 = norms[e], w1 = norms[e + 2], w2 = norms[e + 4], w3 = norms[e + 6];
    bf16x4 v0 = *(const bf16x4*)(T + (long long)s0 * DIN + c);
    bf16x4 v1 = *(const bf16x4*)(T + (long long)s1 * DIN + c);
    bf16x4 v2 = *(const bf16x4*)(T + (long long)s2 * DIN + c);
    bf16x4 v3 = *(const bf16x4*)(T + (long long)s3 * DIN + c);
    a0 += w0 * bf2f(v0[0]) + w1 * bf2f(v1[0]) + w2 * bf2f(v2[0]) + w3 * bf2f(v3[0]);
    a1 += w0 * bf2f(v0[1]) + w1 * bf2f(v1[1]) + w2 * bf2f(v2[1]) + w3 * bf2f(v3[1]);
    a2 += w0 * bf2f(v0[2]) + w1 * bf2f(v1[2]) + w2 * bf2f(v2[2]) + w3 * bf2f(v3[2]);
    a3 += w0 * bf2f(v0[3]) + w1 * bf2f(v1[3]) + w2 * bf2f(v2[3]) + w3 * bf2f(v3[3]);
  }
  for (; e < end; e += 2) {
    int s = srcs[e];
    float w = norms[e];
    bf16x4 v = *(const bf16x4*)(T + (long long)s * DIN + c);
    a0 += w * bf2f(v[0]); a1 += w * bf2f(v[1]);
    a2 += w * bf2f(v[2]); a3 += w * bf2f(v[3]);
  }
  a0 += __shfl_xor(a0, 32, 64); a1 += __shfl_xor(a1, 32, 64);
  a2 += __shfl_xor(a2, 32, 64); a3 += __shfl_xor(a3, 32, 64);
  if (h == 0) {
    float sw = dinv[i] * dinv[i];
    bf16x4 sv = *(const bf16x4*)(T + (long long)i * DIN + c);
    bf16x4 o;
    o[0] = f2bf(a0 + sw * bf2f(sv[0]));
    o[1] = f2bf(a1 + sw * bf2f(sv[1]));
    o[2] = f2bf(a2 + sw * bf2f(sv[2]));
    o[3] = f2bf(a3 + sw * bf2f(sv[3]));
    *(bf16x4*)(out + (long long)i * DIN + c) = o;
  }
}

__global__ __launch_bounds__(256) void k_agg256(const short* __restrict__ T,
                                                const int* __restrict__ rowptr,
                                                const int* __restrict__ srcs,
                                                const float* __restrict__ norms,
                                                const float* __restrict__ dinv,
                                                short* __restrict__ out, int n) {
  int wv = threadIdx.x >> 6, lane = threadIdx.x & 63;
  int i = blockIdx.x * 4 + wv;
  if (i >= n) return;
  int h = lane >> 5;
  int c = (lane & 31) * 8;
  float acc[8];
#pragma unroll
  for (int k = 0; k < 8; ++k) acc[k] = 0.f;
  int e = rowptr[i] + h, end = rowptr[i + 1];
  for (; e + 6 < end; e += 8) {
    int s0 = srcs[e], s1 = srcs[e + 2], s2 = srcs[e + 4], s3 = srcs[e + 6];
    float w0 = norms[e], w1 = norms[e + 2], w2 = norms[e + 4], w3 = norms[e + 6];
    bf16x8 v0 = *(const bf16x8*)(T + (long long)s0 * DH + c);
    bf16x8 v1 = *(const bf16x8*)(T + (long long)s1 * DH + c);
    bf16x8 v2 = *(const bf16x8*)(T + (long long)s2 * DH + c);
    bf16x8 v3 = *(const bf16x8*)(T + (long long)s3 * DH + c);
#pragma unroll
    for (int k = 0; k < 8; ++k)
      acc[k] += w0 * bf2f(v0[k]) + w1 * bf2f(v1[k]) +
                w2 * bf2f(v2[k]) + w3 * bf2f(v3[k]);
  }
  for (; e < end; e += 2) {
    int s = srcs[e];
    float w = norms[e];
    bf16x8 v = *(const bf16x8*)(T + (long long)s * DH + c);
#pragma unroll
    for (int k = 0; k < 8; ++k) acc[k] += w * bf2f(v[k]);
  }
#pragma unroll
  for (int k = 0; k < 8; ++k) acc[k] += __shfl_xor(acc[k], 32, 64);
  if (h == 0) {
    float sw = dinv[i] * dinv[i];
    bf16x8 sv = *(const bf16x8*)(T + (long long)i * DH + c);
    bf16x8 o;
#pragma unroll
    for (int k = 0; k < 8; ++k) o[k] = f2bf(acc[k] + sw * bf2f(sv[k]));
    *(bf16x8*)(out + (long long)i * DH + c) = o;
  }
}

// ------- layer-1 GEMM + epilogue: h1 = LN(relu(Sx@W1+b1) + x@Wres + bres) ----
// 1 wave/block, 16 rows x 256 cols (16 frags). Two sequential K-loops share
// one accumulator (phase A result folded in before phase B accumulates).

__global__ __launch_bounds__(64) void k_gemm_ln1(
    const short* __restrict__ Sx, const short* __restrict__ xb,
    const short* __restrict__ W1t, const short* __restrict__ Wrt,
    const float* __restrict__ b1, const float* __restrict__ bres,
    const float* __restrict__ g1, const float* __restrict__ be1,
    short* __restrict__ h1b, int M) {
  int lane = threadIdx.x & 63;
  int lr = lane & 15, lg = lane >> 4;
  int bm = blockIdx.x * 16;
  int ar = min(bm + lr, M - 1);

  f32x4 acc[16] = {};
#pragma unroll
  for (int ks = 0; ks < 4; ++ks) {
    bf16x8 a = *(const bf16x8*)(Sx + (long long)ar * DIN + ks * 32 + lg * 8);
#pragma unroll
    for (int ni = 0; ni < 16; ++ni) {
      bf16x8 b = *(const bf16x8*)(W1t + (ni * 16 + lr) * DIN + ks * 32 + lg * 8);
      acc[ni] = __builtin_amdgcn_mfma_f32_16x16x32_bf16(a, b, acc[ni], 0, 0, 0);
    }
  }
#pragma unroll
  for (int ni = 0; ni < 16; ++ni) {
    int col = ni * 16 + lr;
    float bb = b1[col], br = bres[col];
#pragma unroll
    for (int j = 0; j < 4; ++j)
      acc[ni][j] = fmaxf(acc[ni][j] + bb, 0.f) + br;
  }
#pragma unroll
  for (int ks = 0; ks < 4; ++ks) {
    bf16x8 a = *(const bf16x8*)(xb + (long long)ar * DIN + ks * 32 + lg * 8);
#pragma unroll
    for (int ni = 0; ni < 16; ++ni) {
      bf16x8 b = *(const bf16x8*)(Wrt + (ni * 16 + lr) * DIN + ks * 32 + lg * 8);
      acc[ni] = __builtin_amdgcn_mfma_f32_16x16x32_bf16(a, b, acc[ni], 0, 0, 0);
    }
  }
  // LN per row (row lives in one 16-lane group), write bf16
#pragma unroll
  for (int j = 0; j < 4; ++j) {
    int r = bm + lg * 4 + j;
    float s1 = 0.f, s2 = 0.f;
#pragma unroll
    for (int ni = 0; ni < 16; ++ni) {
      float v = acc[ni][j];
      s1 += v; s2 += v * v;
    }
#pragma unroll
    for (int m = 1; m < 16; m <<= 1) {
      s1 += __shfl_xor(s1, m, 64);
      s2 += __shfl_xor(s2, m, 64);
    }
    float mu = s1 * (1.f / 256.f);
    float rs = rsqrtf(s2 * (1.f / 256.f) - mu * mu + LN_EPS);
    if (r < M) {
#pragma unroll
      for (int ni = 0; ni < 16; ++ni) {
        int col = ni * 16 + lr;
        float y = (acc[ni][j] - mu) * rs * g1[col] + be1[col];
        h1b[(long long)r * DH + col] = f2bf(y);
      }
    }
  }
}

// ------- layer-2 GEMM + epilogue: out = LN(Sh1@W2 + b2 + h1) (f32) ----------

__global__ __launch_bounds__(64) void k_gemm_ln2(
    const short* __restrict__ Sh1, const short* __restrict__ h1b,
    const short* __restrict__ W2t, const float* __restrict__ b2,
    const float* __restrict__ g2, const float* __restrict__ be2,
    float* __restrict__ out, int M) {
  int lane = threadIdx.x & 63;
  int lr = lane & 15, lg = lane >> 4;
  int bm = blockIdx.x * 16;
  int ar = min(bm + lr, M - 1);

  f32x4 acc[16] = {};
#pragma unroll
  for (int ks = 0; ks < 8; ++ks) {
    bf16x8 a = *(const bf16x8*)(Sh1 + (long long)ar * DH + ks * 32 + lg * 8);
#pragma unroll
    for (int ni = 0; ni < 16; ++ni) {
      bf16x8 b = *(const bf16x8*)(W2t + (ni * 16 + lr) * DH + ks * 32 + lg * 8);
      acc[ni] = __builtin_amdgcn_mfma_f32_16x16x32_bf16(a, b, acc[ni], 0, 0, 0);
    }
  }
  // + b2 + residual h1
#pragma unroll
  for (int j = 0; j < 4; ++j) {
    int rr = min(bm + lg * 4 + j, M - 1);
#pragma unroll
    for (int ni = 0; ni < 16; ++ni) {
      int col = ni * 16 + lr;
      acc[ni][j] += b2[col] + bf2f(h1b[(long long)rr * DH + col]);
    }
  }
#pragma unroll
  for (int j = 0; j < 4; ++j) {
    int r = bm + lg * 4 + j;
    float s1 = 0.f, s2 = 0.f;
#pragma unroll
    for (int ni = 0; ni < 16; ++ni) {
      float v = acc[ni][j];
      s1 += v; s2 += v * v;
    }
#pragma unroll
    for (int m = 1; m < 16; m <<= 1) {
      s1 += __shfl_xor(s1, m, 64);
      s2 += __shfl_xor(s2, m, 64);
    }
    float mu = s1 * (1.f / 256.f);
    float rs = rsqrtf(s2 * (1.f / 256.f) - mu * mu + LN_EPS);
    if (r < M) {
#pragma unroll
      for (int ni = 0; ni < 16; ++ni) {
        int col = ni * 16 + lr;
        out[(long long)r * DH + col] = (acc[ni][j] - mu) * rs * g2[col] + be2[col];
      }
    }
  }
}

// ---------------- launcher ----------------

extern "C" void kernel_launch(void* const* d_in, const int* in_sizes, int n_in,
                              void* d_out, int out_size, void* d_ws,
                              size_t ws_size, hipStream_t stream) {
  const float* x    = (const float*)d_in[0];
  const void*  ei   = d_in[1];
  const float* ew   = (const float*)d_in[2];
  const float* W1   = (const float*)d_in[3];
  const float* b1   = (const float*)d_in[4];
  const float* W2   = (const float*)d_in[5];
  const float* b2   = (const float*)d_in[6];
  const float* Wres = (const float*)d_in[7];
  const float* bres = (const float*)d_in[8];
  const float* g1   = (const float*)d_in[9];
  const float* be1  = (const float*)d_in[10];
  const float* g2   = (const float*)d_in[11];
  const float* be2  = (const float*)d_in[12];

  const int N = in_sizes[0] / DIN;
  const int E = in_sizes[2];

  char* ws = (char*)d_ws;
  auto alloc = [&](size_t bytes) -> char* {
    char* p = ws;
    ws += (bytes + 255) & ~(size_t)255;
    return p;
  };
  short* xb     = (short*)alloc((size_t)N * DIN * 2);
  short* W1t    = (short*)alloc((size_t)DIN * DH * 2);
  short* Wrt    = (short*)alloc((size_t)DIN * DH * 2);
  short* W2t    = (short*)alloc((size_t)DH * DH * 2);
  short* Sx     = (short*)alloc((size_t)N * DIN * 2);
  short* h1b    = (short*)alloc((size_t)N * DH * 2);
  short* Sh1    = (short*)alloc((size_t)N * DH * 2);
  int*   cnt    = (int*)alloc((size_t)N * 8);   // cnt[N] + deg[N]
  float* deg    = (float*)(cnt + N);            // becomes dinv in k_scan
  int*   rowptr = (int*)alloc((size_t)(N + 1) * 4);
  int*   cursor = (int*)alloc((size_t)(N + 1) * 4);
  int*   srcs   = (int*)alloc((size_t)E * 4);
  float* norms  = (float*)alloc((size_t)E * 4);

  hipMemsetAsync(cnt, 0, (size_t)N * 8, stream);

  int prep_items = N * DIN / 8 + 2 * DIN * DH + DH * DH + E;
  k_prep<<<(prep_items + 255) / 256, 256, 0, stream>>>(
      x, xb, W1, Wres, W2, W1t, Wrt, W2t, ei, ew, deg, cnt, N, E);
  k_scan<<<1, 1024, 0, stream>>>(cnt, deg, rowptr, cursor, N);
  k_fill<<<(E + 255) / 256, 256, 0, stream>>>(ei, ew, deg, cursor, srcs, norms, E);

  k_agg128<<<(N + 3) / 4, 256, 0, stream>>>(xb, rowptr, srcs, norms, deg, Sx, N);
  k_gemm_ln1<<<(N + 15) / 16, 64, 0, stream>>>(Sx, xb, W1t, Wrt, b1, bres, g1,
                                               be1, h1b, N);
  k_agg256<<<(N + 3) / 4, 256, 0, stream>>>(h1b, rowptr, srcs, norms, deg, Sh1, N);
  k_gemm_ln2<<<(N + 15) / 16, 64, 0, stream>>>(Sh1, h1b, W2t, b2, g2, be2,
                                               (float*)d_out, N);
}